// Round 10
// baseline (537.110 us; speedup 1.0000x reference)
//
#include <hip/hip_runtime.h>

// =====================================================================
// GCN forward, fully fused per layer using A(hW) = (Ah)W:
//   state hs = bf16(dinv * h); per layer one kernel:
//   gather-sum hs -> v = dinv*(sum+self) -> LDS tile -> MFMA @ W ->
//   +b +residual(hs/dinv) -> LayerNorm -> ReLU -> hs_out (or @Wo -> out).
// CSR build = bucketed counting sort (no global atomics).
// Agg gather is at compulsory-miss floor (203MB @ ~2.45TB/s, r2-r9).
// =====================================================================

typedef __attribute__((ext_vector_type(8))) short short8;
typedef __attribute__((ext_vector_type(4))) float f32x4;

#define CHUNK 4096
#define BSH   9

__device__ __forceinline__ unsigned short f2bf_rne(float f){
  unsigned x = __float_as_uint(f);
  unsigned r = (x + 0x7FFFu + ((x >> 16) & 1u)) >> 16;
  return (unsigned short)r;
}
__device__ __forceinline__ float bf_lo(unsigned u){ return __uint_as_float(u << 16); }
__device__ __forceinline__ float bf_hi(unsigned u){ return __uint_as_float(u & 0xFFFF0000u); }
__device__ __forceinline__ float bfu(unsigned short u){ return __uint_as_float(((unsigned)u) << 16); }

__device__ __forceinline__ int wave_incl_scan(int v, int lane){
#pragma unroll
  for (int off = 1; off < 64; off <<= 1){
    int t = __shfl_up(v, off, 64);
    if (lane >= off) v += t;
  }
  return v;
}

__device__ __forceinline__ int blockscan256(int v, int tid, int* tot){
  int lane = tid & 63, wid = tid >> 6;
  __shared__ int ws[4];
  int incl = wave_incl_scan(v, lane);
  if (lane == 63) ws[wid] = incl;
  __syncthreads();
  int w0 = ws[0], w1 = ws[1], w2 = ws[2], w3 = ws[3];
  __syncthreads();
  int wofs = (wid > 0 ? w0 : 0) + (wid > 1 ? w1 : 0) + (wid > 2 ? w2 : 0);
  *tot = w0 + w1 + w2 + w3;
  return wofs + incl - v;
}

// ---------------- CSR build: bucketed counting sort ----------------
__global__ __launch_bounds__(256) void k_bhist(const int* __restrict__ ei, int E, int n,
                                               int NB, int NCH, int* __restrict__ bh){
  __shared__ int hist[512];
  int tid = threadIdx.x, b = blockIdx.x;
  for (int j = tid; j < NB; j += 256) hist[j] = 0;
  __syncthreads();
  int e0 = b*CHUNK;
  for (int i = tid; i < CHUNK; i += 256){
    int e = e0 + i;
    if (e < E){
      int d = ei[E + e];
      if ((unsigned)d < (unsigned)n) atomicAdd(&hist[d >> BSH], 1);
    }
  }
  __syncthreads();
  for (int j = tid; j < NB; j += 256) bh[(size_t)j*NCH + b] = hist[j];
}

__global__ __launch_bounds__(256) void k_scanB1(int* __restrict__ bh, int* __restrict__ btot,
                                                int NCH){
  int j = blockIdx.x, tid = threadIdx.x;
  int carry = 0;
  for (int base = 0; base < NCH; base += 256){
    int idx = base + tid;
    int v = (idx < NCH) ? bh[(size_t)j*NCH + idx] : 0;
    int tot, ex = blockscan256(v, tid, &tot);
    if (idx < NCH) bh[(size_t)j*NCH + idx] = carry + ex;
    carry += tot;
  }
  if (tid == 0) btot[j] = carry;
}

__global__ __launch_bounds__(512) void k_scanB2(const int* __restrict__ btot,
                                                int* __restrict__ bstart, int NB, int E,
                                                int* __restrict__ rp, int n){
  int tid = threadIdx.x;
  int lane = tid & 63, wid = tid >> 6;
  __shared__ int ws[8];
  int carry = 0;
  for (int base = 0; base < NB; base += 512){
    int idx = base + tid;
    int v = (idx < NB) ? btot[idx] : 0;
    int incl = wave_incl_scan(v, lane);
    if (lane == 63) ws[wid] = incl;
    __syncthreads();
    int wofs = 0;
#pragma unroll
    for (int i = 0; i < 8; i++) if (i < wid) wofs += ws[i];
    int tot = ws[0]+ws[1]+ws[2]+ws[3]+ws[4]+ws[5]+ws[6]+ws[7];
    __syncthreads();
    if (idx < NB) bstart[idx] = carry + wofs + incl - v;
    carry += tot;
  }
  if (tid == 0){ bstart[NB] = E; rp[n] = E; }
}

// scatter packed word: s | (dlocal << 17)   (n < 2^17, dlocal < 512)
__global__ __launch_bounds__(256) void k_bscatter(const int* __restrict__ ei, int E, int n,
    int NB, int NCH, const int* __restrict__ bh, const int* __restrict__ bstart,
    unsigned* __restrict__ pairs){
  __shared__ int base_l[512];
  int tid = threadIdx.x, b = blockIdx.x;
  for (int j = tid; j < NB; j += 256) base_l[j] = bstart[j] + bh[(size_t)j*NCH + b];
  __syncthreads();
  int e0 = b*CHUNK;
  for (int i = tid; i < CHUNK; i += 256){
    int e = e0 + i;
    if (e < E){
      int d = ei[E + e], s = ei[e];
      if ((unsigned)d < (unsigned)n && (unsigned)s < (unsigned)n){
        int pos = atomicAdd(&base_l[d >> BSH], 1);
        pairs[pos] = (unsigned)s | ((unsigned)(d & 511) << 17);
      }
    }
  }
}

// merged: per-bucket counts -> rp + dinv, then fill col
__global__ __launch_bounds__(256) void k_bnode(const unsigned* __restrict__ pairs,
    const int* __restrict__ bstart, int* __restrict__ rp, float* __restrict__ dinv,
    int* __restrict__ col, int n){
  __shared__ int cnt_l[512];
  __shared__ int loc[512];
  int j = blockIdx.x, tid = threadIdx.x;
  cnt_l[tid] = 0; cnt_l[tid + 256] = 0;
  __syncthreads();
  int p0 = bstart[j], p1 = bstart[j+1];
  for (int p = p0 + tid; p < p1; p += 256)
    atomicAdd(&cnt_l[pairs[p] >> 17], 1);
  __syncthreads();
  int carry = 0;
  int nbase = j << BSH;
  for (int base = 0; base < 512; base += 256){
    int v = cnt_l[base + tid];
    int tot, ex = blockscan256(v, tid, &tot);
    int node = nbase + base + tid;
    int start = p0 + carry + ex;
    if (node < n){
      rp[node] = start;
      dinv[node] = rsqrtf((float)v + 1.0f);
    }
    loc[base + tid] = start;
    carry += tot;
  }
  __syncthreads();
  for (int p = p0 + tid; p < p1; p += 256){
    unsigned pr = pairs[p];
    int pos = atomicAdd(&loc[pr >> 17], 1);
    col[pos] = (int)(pr & 0x1FFFFu);
  }
}

// ------- all weight preps in one launch: Wc0/1/2 [128,128] + W_in [64,128] -------
__global__ void k_prepAll(const float* __restrict__ W0, const float* __restrict__ W1,
                          const float* __restrict__ W2, const float* __restrict__ Wi,
                          unsigned short* __restrict__ T0, unsigned short* __restrict__ T1,
                          unsigned short* __restrict__ T2, unsigned short* __restrict__ Ti){
  int b = blockIdx.x, t = threadIdx.x;
  if (b < 192){
    const float* W = (b < 64) ? W0 : ((b < 128) ? W1 : W2);
    unsigned short* T = (b < 64) ? T0 : ((b < 128) ? T1 : T2);
    int idx = (b & 63)*256 + t;
    int k = idx >> 7, c = idx & 127;
    T[c*128 + k] = f2bf_rne(W[idx]);
  } else {
    int idx = (b - 192)*256 + t;       // 8192 elems
    int k = idx >> 7, c = idx & 127;
    Ti[c*64 + k] = f2bf_rne(Wi[idx]);
  }
}

// ---- input GEMM (MFMA): hs0 = dinv * relu(X @ Wi + b), 256 rows/block ----
__global__ __launch_bounds__(256) void k_gemm_in_mfma(
    const float* __restrict__ X,             // [n,64] fp32
    const unsigned short* __restrict__ Wt,   // [128,64] bf16 [c][k]
    const float* __restrict__ b,
    const float* __restrict__ dinv,
    unsigned short* __restrict__ hs, int n){
  __shared__ unsigned short Wl[128*64];
  int tid = threadIdx.x;
  for (int i = tid; i < 1024; i += 256){
    int c = i >> 3, kc = i & 7;
    *(uint4*)&Wl[c*64 + (kc ^ (c & 7))*8] = *(const uint4*)&Wt[c*64 + kc*8];
  }
  __syncthreads();
  int wid = tid >> 6, lane = tid & 63;
  int kgrp = lane >> 4;
  int colb = lane & 15;
  int base = blockIdx.x*256 + wid*64;
  for (int mi = 0; mi < 4; mi++){
    int r0 = base + mi*16;
    int arow = r0 + (lane & 15);
    if (arow >= n) arow = n - 1;
    f32x4 acc[8];
#pragma unroll
    for (int cf = 0; cf < 8; cf++) acc[cf] = (f32x4){0.f,0.f,0.f,0.f};
#pragma unroll
    for (int kk = 0; kk < 2; kk++){
      const float* ap = &X[(size_t)arow*64 + kk*32 + kgrp*8];
      float4 a0 = *(const float4*)ap;
      float4 a1 = *(const float4*)(ap + 4);
      short8 afrag;
      afrag[0] = (short)f2bf_rne(a0.x); afrag[1] = (short)f2bf_rne(a0.y);
      afrag[2] = (short)f2bf_rne(a0.z); afrag[3] = (short)f2bf_rne(a0.w);
      afrag[4] = (short)f2bf_rne(a1.x); afrag[5] = (short)f2bf_rne(a1.y);
      afrag[6] = (short)f2bf_rne(a1.z); afrag[7] = (short)f2bf_rne(a1.w);
      int kc = kk*4 + kgrp;
#pragma unroll
      for (int cf = 0; cf < 8; cf++){
        int c = cf*16 + (lane & 15);
        short8 bfrag = *(const short8*)&Wl[c*64 + (kc ^ (c & 7))*8];
        acc[cf] = __builtin_amdgcn_mfma_f32_16x16x32_bf16(afrag, bfrag, acc[cf], 0, 0, 0);
      }
    }
    int rbase = r0 + (lane >> 4)*4;
#pragma unroll
    for (int reg = 0; reg < 4; reg++){
      int r = rbase + reg;
      if (r < n){
        float dv = dinv[r];
#pragma unroll
        for (int cf = 0; cf < 8; cf++){
          int c = cf*16 + colb;
          hs[(size_t)r*128 + c] = f2bf_rne(fmaxf(acc[cf][reg] + b[c], 0.f) * dv);
        }
      }
    }
  }
}

// ---- fused layer: gather hs -> v -> MFMA @ W -> +b +resid -> LN -> ReLU ----
// LAST=0: write hs_out = y*dinv ; LAST=1: out = y @ Wo + bo
template<int LAST>
__global__ __launch_bounds__(256) void k_layer(
    const unsigned short* __restrict__ hin,   // hs in, [n,128] bf16
    unsigned short* __restrict__ hout,
    const float* __restrict__ dinv,
    const int* __restrict__ rp, const int* __restrict__ col,
    const unsigned short* __restrict__ Wt,    // [128,128] bf16 [c][k]
    const float* __restrict__ bc, const float* __restrict__ g,
    const float* __restrict__ be,
    const float* __restrict__ Wo, const float* __restrict__ bo,
    float* __restrict__ out, int n){
  __shared__ unsigned tile[4][16*64];        // per-wave 16 nodes x 128 bf16 (4KB)
  int tid = threadIdx.x;
  int wid = tid >> 6, lane = tid & 63;
  unsigned* T = tile[wid];
  const unsigned* HS = (const unsigned*)hin;
  int nb0 = blockIdx.x*64 + wid*16;

  // ---- phase 1: aggregate 16 nodes (proven gather loop) ----
  for (int i = 0; i < 16; ++i){
    int node = nb0 + i;
    float ax = 0.f, ay = 0.f, dd = 0.f;
    if (node < n){
      unsigned vs = HS[(size_t)node*64 + lane];   // self (hs = dinv*h)
      ax = bf_lo(vs); ay = bf_hi(vs);
      dd = dinv[node];
      int e = rp[node], end = rp[node+1];
      for (; e + 8 <= end; e += 8){
        int s0 = col[e+0], s1 = col[e+1], s2 = col[e+2], s3 = col[e+3];
        int s4 = col[e+4], s5 = col[e+5], s6 = col[e+6], s7 = col[e+7];
        unsigned a0 = HS[(size_t)s0*64 + lane];
        unsigned a1 = HS[(size_t)s1*64 + lane];
        unsigned a2 = HS[(size_t)s2*64 + lane];
        unsigned a3 = HS[(size_t)s3*64 + lane];
        unsigned a4 = HS[(size_t)s4*64 + lane];
        unsigned a5 = HS[(size_t)s5*64 + lane];
        unsigned a6 = HS[(size_t)s6*64 + lane];
        unsigned a7 = HS[(size_t)s7*64 + lane];
        ax += bf_lo(a0); ay += bf_hi(a0);
        ax += bf_lo(a1); ay += bf_hi(a1);
        ax += bf_lo(a2); ay += bf_hi(a2);
        ax += bf_lo(a3); ay += bf_hi(a3);
        ax += bf_lo(a4); ay += bf_hi(a4);
        ax += bf_lo(a5); ay += bf_hi(a5);
        ax += bf_lo(a6); ay += bf_hi(a6);
        ax += bf_lo(a7); ay += bf_hi(a7);
      }
      for (; e < end; ++e){
        unsigned a0 = HS[(size_t)col[e]*64 + lane];
        ax += bf_lo(a0); ay += bf_hi(a0);
      }
    }
    // v = dinv_d * (sum_src hs + hs_self)  (feats 2*lane, 2*lane+1)
    float v0 = ax * dd, v1 = ay * dd;
    // swizzled LDS store (16B-chunk XOR by row&7): chunk fc = lane>>2
    int idx = i*64 + (((lane >> 2) ^ (i & 7)) << 2) + (lane & 3);
    T[idx] = (unsigned)f2bf_rne(v0) | ((unsigned)f2bf_rne(v1) << 16);
  }
  asm volatile("s_waitcnt lgkmcnt(0)" ::: "memory");
  __builtin_amdgcn_sched_barrier(0);

  // ---- phase 2: [16 nodes x 128] @ W[128x128] via MFMA, B-frags from L2 ----
  int r16 = lane & 15, kgrp = lane >> 4;
  f32x4 acc[8];
#pragma unroll
  for (int cf = 0; cf < 8; cf++) acc[cf] = (f32x4){0.f,0.f,0.f,0.f};
#pragma unroll
  for (int kk = 0; kk < 4; ++kk){
    int fc = kk*4 + kgrp;
    short8 afrag = *(const short8*)&T[r16*64 + ((fc ^ (r16 & 7)) << 2)];
#pragma unroll
    for (int cf = 0; cf < 8; cf++){
      int c = cf*16 + r16;
      short8 bfrag = *(const short8*)&Wt[c*128 + kk*32 + kgrp*8];
      acc[cf] = __builtin_amdgcn_mfma_f32_16x16x32_bf16(afrag, bfrag, acc[cf], 0, 0, 0);
    }
  }

  // ---- phase 3: epilogue in C layout: row = nb0 + kgrp*4 + reg, col = cf*16+r16 ----
  float bbv[8], ggv[8], bev[8];
#pragma unroll
  for (int cf = 0; cf < 8; cf++){
    int c = cf*16 + r16;
    bbv[cf] = bc[c]; ggv[cf] = g[c]; bev[cf] = be[c];
  }
#pragma unroll
  for (int reg = 0; reg < 4; reg++){
    int r = nb0 + kgrp*4 + reg;
    bool ok = (r < n);
    float dv = ok ? dinv[r] : 1.f;
    float rdv = 1.0f / dv;
    float val[8];
    float s = 0.f;
#pragma unroll
    for (int cf = 0; cf < 8; cf++){
      float resid = ok ? bfu(hin[(size_t)r*128 + cf*16 + r16]) * rdv : 0.f;
      val[cf] = acc[cf][reg] + bbv[cf] + resid;
      s += val[cf];
    }
#pragma unroll
    for (int m = 1; m < 16; m <<= 1) s += __shfl_xor(s, m, 64);
    float mu = s * (1.0f/128.0f);
    float q = 0.f;
#pragma unroll
    for (int cf = 0; cf < 8; cf++){
      float d = val[cf] - mu;
      q += d*d;
    }
#pragma unroll
    for (int m = 1; m < 16; m <<= 1) q += __shfl_xor(q, m, 64);
    float rstd = rsqrtf(q * (1.0f/128.0f) + 1e-5f);
    if (!LAST){
      if (ok){
#pragma unroll
        for (int cf = 0; cf < 8; cf++){
          float y = fmaxf(fmaf((val[cf]-mu)*rstd, ggv[cf], bev[cf]), 0.f);
          hout[(size_t)r*128 + cf*16 + r16] = f2bf_rne(y * dv);
        }
      }
    } else {
      float p0 = 0.f, p1 = 0.f;
#pragma unroll
      for (int cf = 0; cf < 8; cf++){
        float y = fmaxf(fmaf((val[cf]-mu)*rstd, ggv[cf], bev[cf]), 0.f);
        int c = cf*16 + r16;
        p0 = fmaf(y, Wo[c*2+0], p0);
        p1 = fmaf(y, Wo[c*2+1], p1);
      }
#pragma unroll
      for (int m = 1; m < 16; m <<= 1){
        p0 += __shfl_xor(p0, m, 64);
        p1 += __shfl_xor(p1, m, 64);
      }
      if (ok && r16 == 0){
        out[r*2+0] = p0 + bo[0];
        out[r*2+1] = p1 + bo[1];
      }
    }
  }
}

// =====================================================================
extern "C" void kernel_launch(void* const* d_in, const int* in_sizes, int n_in,
                              void* d_out, int out_size, void* d_ws, size_t ws_size,
                              hipStream_t stream){
  const float* x      = (const float*)d_in[0];
  const int*   ei     = (const int*)d_in[1];
  const float* W_in   = (const float*)d_in[2];
  const float* b_in   = (const float*)d_in[3];
  const float* W_out  = (const float*)d_in[4];
  const float* b_out  = (const float*)d_in[5];
  const float* Wc[3] = {(const float*)d_in[6],  (const float*)d_in[10], (const float*)d_in[14]};
  const float* bc[3] = {(const float*)d_in[7],  (const float*)d_in[11], (const float*)d_in[15]};
  const float* g[3]  = {(const float*)d_in[8],  (const float*)d_in[12], (const float*)d_in[16]};
  const float* be[3] = {(const float*)d_in[9],  (const float*)d_in[13], (const float*)d_in[17]};
  const int n = in_sizes[0] / 64;
  const int E = in_sizes[1] / 2;
  const int NB  = (n + 511) >> BSH;
  const int NCH = (E + CHUNK - 1) / CHUNK;

  char* ws = (char*)d_ws;
  size_t off = 0;
  auto alloc = [&](size_t bytes)->char*{
    char* p = ws + off;
    off += (bytes + 511) & ~size_t(511);
    return p;
  };
  float* dinv   = (float*)alloc((size_t)n*4);
  int*   rp     = (int*)  alloc((size_t)(n+1)*4);
  int*   col    = (int*)  alloc((size_t)E*4);
  unsigned* pairs = (unsigned*)alloc((size_t)E*4);
  int*   bh     = (int*)  alloc((size_t)NB*NCH*4);
  int*   btot   = (int*)  alloc((size_t)NB*4);
  int*   bstart = (int*)  alloc((size_t)(NB+1)*4);
  unsigned short* hsA = (unsigned short*)alloc((size_t)n*128*2);
  unsigned short* hsB = (unsigned short*)alloc((size_t)n*128*2);
  unsigned short* Wt[3];
  for (int l = 0; l < 3; ++l) Wt[l] = (unsigned short*)alloc(128*128*2);
  unsigned short* Wti = (unsigned short*)alloc(128*64*2);
  (void)ws_size; (void)n_in; (void)out_size;

  // CSR build
  k_bhist   <<<NCH, 256, 0, stream>>>(ei, E, n, NB, NCH, bh);
  k_scanB1  <<<NB, 256, 0, stream>>>(bh, btot, NCH);
  k_scanB2  <<<1, 512, 0, stream>>>(btot, bstart, NB, E, rp, n);
  k_bscatter<<<NCH, 256, 0, stream>>>(ei, E, n, NB, NCH, bh, bstart, pairs);
  k_bnode   <<<NB, 256, 0, stream>>>(pairs, bstart, rp, dinv, col, n);

  // weight preps
  k_prepAll<<<224, 256, 0, stream>>>(Wc[0], Wc[1], Wc[2], W_in, Wt[0], Wt[1], Wt[2], Wti);

  // input layer -> hsA
  k_gemm_in_mfma<<<(n+255)/256, 256, 0, stream>>>(x, Wti, b_in, dinv, hsA, n);

  int nlb = (n + 63)/64;
  // layer 0: hsA -> hsB
  k_layer<0><<<nlb, 256, 0, stream>>>(hsA, hsB, dinv, rp, col, Wt[0],
            bc[0], g[0], be[0], nullptr, nullptr, nullptr, n);
  // layer 1: hsB -> hsA
  k_layer<0><<<nlb, 256, 0, stream>>>(hsB, hsA, dinv, rp, col, Wt[1],
            bc[1], g[1], be[1], nullptr, nullptr, nullptr, n);
  // layer 2 (fused output GEMM): hsA -> out
  k_layer<1><<<nlb, 256, 0, stream>>>(hsA, nullptr, dinv, rp, col, Wt[2],
            bc[2], g[2], be[2], W_out, b_out, (float*)d_out, n);
}

// Round 11
// 354.837 us; speedup vs baseline: 1.5137x; 1.5137x over previous
//
#include <hip/hip_runtime.h>

// =====================================================================
// GCN forward: 3x GCNConv(+self-loops, sym-norm) + residual+LN+ReLU.
// h bf16 end-to-end; both GEMMs = bf16 MFMA 16x16x32 (input GEMM reads
// fp32 X directly, converts in-register). CSR build = bucketed counting
// sort with packed (s|dloc) words. Pull aggregation (wave/node, 8-deep
// dword gathers) + fused LN; last layer fuses the [128,2] output GEMM.
// Aggregation is at compulsory-miss floor: FETCH = unique rows x 8 XCDs
// at the ~2.45 TB/s L2-miss-path rate (pinned r2-r10; occupancy-sustained:
// r10's low-occupancy fusion halved it). Do NOT fuse into the gather.
// =====================================================================

typedef __attribute__((ext_vector_type(8))) short short8;
typedef __attribute__((ext_vector_type(4))) float f32x4;

#define CHUNK 4096
#define BSH   9

__device__ __forceinline__ unsigned short f2bf_rne(float f){
  unsigned x = __float_as_uint(f);
  unsigned r = (x + 0x7FFFu + ((x >> 16) & 1u)) >> 16;
  return (unsigned short)r;
}
__device__ __forceinline__ float bf_lo(unsigned u){ return __uint_as_float(u << 16); }
__device__ __forceinline__ float bf_hi(unsigned u){ return __uint_as_float(u & 0xFFFF0000u); }

__device__ __forceinline__ int wave_incl_scan(int v, int lane){
#pragma unroll
  for (int off = 1; off < 64; off <<= 1){
    int t = __shfl_up(v, off, 64);
    if (lane >= off) v += t;
  }
  return v;
}

__device__ __forceinline__ int blockscan256(int v, int tid, int* tot){
  int lane = tid & 63, wid = tid >> 6;
  __shared__ int ws[4];
  int incl = wave_incl_scan(v, lane);
  if (lane == 63) ws[wid] = incl;
  __syncthreads();
  int w0 = ws[0], w1 = ws[1], w2 = ws[2], w3 = ws[3];
  __syncthreads();
  int wofs = (wid > 0 ? w0 : 0) + (wid > 1 ? w1 : 0) + (wid > 2 ? w2 : 0);
  *tot = w0 + w1 + w2 + w3;
  return wofs + incl - v;
}

// ---------------- CSR build: bucketed counting sort ----------------
__global__ __launch_bounds__(256) void k_bhist(const int* __restrict__ ei, int E, int n,
                                               int NB, int NCH, int* __restrict__ bh){
  __shared__ int hist[512];
  int tid = threadIdx.x, b = blockIdx.x;
  for (int j = tid; j < NB; j += 256) hist[j] = 0;
  __syncthreads();
  int e0 = b*CHUNK;
  for (int i = tid; i < CHUNK; i += 256){
    int e = e0 + i;
    if (e < E){
      int d = ei[E + e];
      if ((unsigned)d < (unsigned)n) atomicAdd(&hist[d >> BSH], 1);
    }
  }
  __syncthreads();
  for (int j = tid; j < NB; j += 256) bh[(size_t)j*NCH + b] = hist[j];
}

__global__ __launch_bounds__(256) void k_scanB1(int* __restrict__ bh, int* __restrict__ btot,
                                                int NCH){
  int j = blockIdx.x, tid = threadIdx.x;
  int carry = 0;
  for (int base = 0; base < NCH; base += 256){
    int idx = base + tid;
    int v = (idx < NCH) ? bh[(size_t)j*NCH + idx] : 0;
    int tot, ex = blockscan256(v, tid, &tot);
    if (idx < NCH) bh[(size_t)j*NCH + idx] = carry + ex;
    carry += tot;
  }
  if (tid == 0) btot[j] = carry;
}

__global__ __launch_bounds__(512) void k_scanB2(const int* __restrict__ btot,
                                                int* __restrict__ bstart, int NB, int E,
                                                int* __restrict__ rp, int n){
  int tid = threadIdx.x;
  int lane = tid & 63, wid = tid >> 6;
  __shared__ int ws[8];
  int carry = 0;
  for (int base = 0; base < NB; base += 512){
    int idx = base + tid;
    int v = (idx < NB) ? btot[idx] : 0;
    int incl = wave_incl_scan(v, lane);
    if (lane == 63) ws[wid] = incl;
    __syncthreads();
    int wofs = 0;
#pragma unroll
    for (int i = 0; i < 8; i++) if (i < wid) wofs += ws[i];
    int tot = ws[0]+ws[1]+ws[2]+ws[3]+ws[4]+ws[5]+ws[6]+ws[7];
    __syncthreads();
    if (idx < NB) bstart[idx] = carry + wofs + incl - v;
    carry += tot;
  }
  if (tid == 0){ bstart[NB] = E; rp[n] = E; }
}

// scatter packed word: s | (dlocal << 17)   (n < 2^17, dlocal < 512)
__global__ __launch_bounds__(256) void k_bscatter(const int* __restrict__ ei, int E, int n,
    int NB, int NCH, const int* __restrict__ bh, const int* __restrict__ bstart,
    unsigned* __restrict__ pairs){
  __shared__ int base_l[512];
  int tid = threadIdx.x, b = blockIdx.x;
  for (int j = tid; j < NB; j += 256) base_l[j] = bstart[j] + bh[(size_t)j*NCH + b];
  __syncthreads();
  int e0 = b*CHUNK;
  for (int i = tid; i < CHUNK; i += 256){
    int e = e0 + i;
    if (e < E){
      int d = ei[E + e], s = ei[e];
      if ((unsigned)d < (unsigned)n && (unsigned)s < (unsigned)n){
        int pos = atomicAdd(&base_l[d >> BSH], 1);
        pairs[pos] = (unsigned)s | ((unsigned)(d & 511) << 17);
      }
    }
  }
}

// merged: per-bucket counts -> rp + dinv, then fill col
__global__ __launch_bounds__(256) void k_bnode(const unsigned* __restrict__ pairs,
    const int* __restrict__ bstart, int* __restrict__ rp, float* __restrict__ dinv,
    int* __restrict__ col, int n){
  __shared__ int cnt_l[512];
  __shared__ int loc[512];
  int j = blockIdx.x, tid = threadIdx.x;
  cnt_l[tid] = 0; cnt_l[tid + 256] = 0;
  __syncthreads();
  int p0 = bstart[j], p1 = bstart[j+1];
  for (int p = p0 + tid; p < p1; p += 256)
    atomicAdd(&cnt_l[pairs[p] >> 17], 1);
  __syncthreads();
  int carry = 0;
  int nbase = j << BSH;
  for (int base = 0; base < 512; base += 256){
    int v = cnt_l[base + tid];
    int tot, ex = blockscan256(v, tid, &tot);
    int node = nbase + base + tid;
    int start = p0 + carry + ex;
    if (node < n){
      rp[node] = start;
      dinv[node] = rsqrtf((float)v + 1.0f);
    }
    loc[base + tid] = start;
    carry += tot;
  }
  __syncthreads();
  for (int p = p0 + tid; p < p1; p += 256){
    unsigned pr = pairs[p];
    int pos = atomicAdd(&loc[pr >> 17], 1);
    col[pos] = (int)(pr & 0x1FFFFu);
  }
}

// ------- all weight preps in one launch: Wc0/1/2 [128,128] + W_in [64,128] -------
__global__ void k_prepAll(const float* __restrict__ W0, const float* __restrict__ W1,
                          const float* __restrict__ W2, const float* __restrict__ Wi,
                          unsigned short* __restrict__ T0, unsigned short* __restrict__ T1,
                          unsigned short* __restrict__ T2, unsigned short* __restrict__ Ti){
  int b = blockIdx.x, t = threadIdx.x;
  if (b < 192){
    const float* W = (b < 64) ? W0 : ((b < 128) ? W1 : W2);
    unsigned short* T = (b < 64) ? T0 : ((b < 128) ? T1 : T2);
    int idx = (b & 63)*256 + t;
    int k = idx >> 7, c = idx & 127;
    T[c*128 + k] = f2bf_rne(W[idx]);
  } else {
    int idx = (b - 192)*256 + t;       // 8192 elems
    int k = idx >> 7, c = idx & 127;
    Ti[c*64 + k] = f2bf_rne(Wi[idx]);
  }
}

// ---- input GEMM (MFMA): h = relu(X @ W_in + b_in), fp32 X read + in-reg cvt ----
__global__ __launch_bounds__(256) void k_gemm_in_mfma(
    const float* __restrict__ X,             // [n,64] fp32
    const unsigned short* __restrict__ Wt,   // [128,64] bf16 [c][k]
    const float* __restrict__ b,
    unsigned short* __restrict__ h, int n){
  __shared__ unsigned short Wl[128*64];
  int tid = threadIdx.x;
  for (int i = tid; i < 1024; i += 256){     // 1024 16B chunks
    int c = i >> 3, kc = i & 7;
    *(uint4*)&Wl[c*64 + (kc ^ (c & 7))*8] = *(const uint4*)&Wt[c*64 + kc*8];
  }
  __syncthreads();
  int wid = tid >> 6, lane = tid & 63;
  int r0 = blockIdx.x*64 + wid*16;
  int arow = r0 + (lane & 15);
  if (arow >= n) arow = n - 1;
  int kgrp = lane >> 4;
  f32x4 acc[8];
#pragma unroll
  for (int cf = 0; cf < 8; cf++) acc[cf] = (f32x4){0.f,0.f,0.f,0.f};
#pragma unroll
  for (int kk = 0; kk < 2; kk++){
    const float* ap = &X[(size_t)arow*64 + kk*32 + kgrp*8];
    float4 a0 = *(const float4*)ap;
    float4 a1 = *(const float4*)(ap + 4);
    short8 afrag;
    afrag[0] = (short)f2bf_rne(a0.x); afrag[1] = (short)f2bf_rne(a0.y);
    afrag[2] = (short)f2bf_rne(a0.z); afrag[3] = (short)f2bf_rne(a0.w);
    afrag[4] = (short)f2bf_rne(a1.x); afrag[5] = (short)f2bf_rne(a1.y);
    afrag[6] = (short)f2bf_rne(a1.z); afrag[7] = (short)f2bf_rne(a1.w);
    int kc = kk*4 + kgrp;
#pragma unroll
    for (int cf = 0; cf < 8; cf++){
      int c = cf*16 + (lane & 15);
      short8 bfrag = *(const short8*)&Wl[c*64 + (kc ^ (c & 7))*8];
      acc[cf] = __builtin_amdgcn_mfma_f32_16x16x32_bf16(afrag, bfrag, acc[cf], 0, 0, 0);
    }
  }
  int rbase = r0 + (lane >> 4)*4;
  int colb = lane & 15;
#pragma unroll
  for (int reg = 0; reg < 4; reg++){
    int r = rbase + reg;
    if (r < n){
#pragma unroll
      for (int cf = 0; cf < 8; cf++){
        int c = cf*16 + colb;
        h[(size_t)r*128 + c] = f2bf_rne(fmaxf(acc[cf][reg] + b[c], 0.f));
      }
    }
  }
}

// ------- conv GEMM (MFMA bf16): rows = (h @ W) * dinv[row], bf16 out -------
__global__ __launch_bounds__(256) void k_gemm_h_mfma(
    const unsigned short* __restrict__ h,
    const unsigned short* __restrict__ Wt,
    const float* __restrict__ dinv,
    unsigned short* __restrict__ rows, int n){
  __shared__ unsigned short Wl[128*128];
  int tid = threadIdx.x;
  for (int i = tid; i < 2048; i += 256){
    int c = i >> 4, kc = i & 15;
    *(uint4*)&Wl[c*128 + (kc ^ (c & 7))*8] = *(const uint4*)&Wt[c*128 + kc*8];
  }
  __syncthreads();
  int wid = tid >> 6, lane = tid & 63;
  int r0 = blockIdx.x*64 + wid*16;
  int arow = r0 + (lane & 15);
  if (arow >= n) arow = n - 1;
  int kgrp = lane >> 4;
  f32x4 acc[8];
#pragma unroll
  for (int cf = 0; cf < 8; cf++) acc[cf] = (f32x4){0.f,0.f,0.f,0.f};
#pragma unroll
  for (int kk = 0; kk < 4; kk++){
    short8 afrag = *(const short8*)&h[(size_t)arow*128 + kk*32 + kgrp*8];
    int kc = kk*4 + kgrp;
#pragma unroll
    for (int cf = 0; cf < 8; cf++){
      int c = cf*16 + (lane & 15);
      short8 bfrag = *(const short8*)&Wl[c*128 + (kc ^ (c & 7))*8];
      acc[cf] = __builtin_amdgcn_mfma_f32_16x16x32_bf16(afrag, bfrag, acc[cf], 0, 0, 0);
    }
  }
  int rbase = r0 + (lane >> 4)*4;
  int colb = lane & 15;
#pragma unroll
  for (int reg = 0; reg < 4; reg++){
    int r = rbase + reg;
    if (r < n){
      float sc = dinv[r];
#pragma unroll
      for (int cf = 0; cf < 8; cf++)
        rows[(size_t)r*128 + cf*16 + colb] = f2bf_rne(acc[cf][reg]*sc);
    }
  }
}

// ---- aggregation (wave/node, dword gathers, 8-deep) + bias + residual + LN + ReLU.
// LAST=1: fuse the [128,2] output GEMM instead of writing h.
template<int LAST>
__global__ __launch_bounds__(256) void k_agg_ln(const unsigned short* __restrict__ rows,
    unsigned short* __restrict__ h, const float* __restrict__ dinv,
    const int* __restrict__ rp, const int* __restrict__ col,
    const float* __restrict__ bc, const float* __restrict__ g,
    const float* __restrict__ be,
    const float* __restrict__ Wo, const float* __restrict__ bo,
    float* __restrict__ out, int n){
  int node = blockIdx.x*4 + (threadIdx.x >> 6);
  int lane = threadIdx.x & 63;
  if (node >= n) return;
  const unsigned* R = (const unsigned*)rows;
  unsigned vs = R[(size_t)node*64 + lane];     // self-loop (pre-scaled)
  float ax = bf_lo(vs), ay = bf_hi(vs);
  int e = rp[node], end = rp[node+1];
  for (; e + 8 <= end; e += 8){
    int s0 = col[e+0], s1 = col[e+1], s2 = col[e+2], s3 = col[e+3];
    int s4 = col[e+4], s5 = col[e+5], s6 = col[e+6], s7 = col[e+7];
    unsigned a0 = R[(size_t)s0*64 + lane];
    unsigned a1 = R[(size_t)s1*64 + lane];
    unsigned a2 = R[(size_t)s2*64 + lane];
    unsigned a3 = R[(size_t)s3*64 + lane];
    unsigned a4 = R[(size_t)s4*64 + lane];
    unsigned a5 = R[(size_t)s5*64 + lane];
    unsigned a6 = R[(size_t)s6*64 + lane];
    unsigned a7 = R[(size_t)s7*64 + lane];
    ax += bf_lo(a0); ay += bf_hi(a0);
    ax += bf_lo(a1); ay += bf_hi(a1);
    ax += bf_lo(a2); ay += bf_hi(a2);
    ax += bf_lo(a3); ay += bf_hi(a3);
    ax += bf_lo(a4); ay += bf_hi(a4);
    ax += bf_lo(a5); ay += bf_hi(a5);
    ax += bf_lo(a6); ay += bf_hi(a6);
    ax += bf_lo(a7); ay += bf_hi(a7);
  }
  for (; e < end; ++e){
    unsigned a0 = R[(size_t)col[e]*64 + lane];
    ax += bf_lo(a0); ay += bf_hi(a0);
  }
  float di = dinv[node];
  float2 bb = ((const float2*)bc)[lane];
  unsigned* H = (unsigned*)h;
  unsigned iu = H[(size_t)node*64 + lane];
  float vx = fmaf(ax, di, bb.x) + bf_lo(iu);
  float vy = fmaf(ay, di, bb.y) + bf_hi(iu);
  float s1 = vx + vy;
#pragma unroll
  for (int off=32; off; off>>=1) s1 += __shfl_xor(s1, off, 64);
  float mu = s1 * (1.0f/128.0f);
  float dx = vx - mu, dy = vy - mu;
  float q = dx*dx + dy*dy;
#pragma unroll
  for (int off=32; off; off>>=1) q += __shfl_xor(q, off, 64);
  float rstd = rsqrtf(q * (1.0f/128.0f) + 1e-5f);
  float2 gg = ((const float2*)g)[lane];
  float2 eb = ((const float2*)be)[lane];
  float ox = fmaxf(fmaf(dx*rstd, gg.x, eb.x), 0.f);
  float oy = fmaxf(fmaf(dy*rstd, gg.y, eb.y), 0.f);
  if (!LAST){
    H[(size_t)node*64 + lane] = (unsigned)f2bf_rne(ox) | ((unsigned)f2bf_rne(oy) << 16);
  } else {
    float4 w = ((const float4*)Wo)[lane];   // Wo rows 2*lane, 2*lane+1
    float p0 = ox*w.x + oy*w.z;
    float p1 = ox*w.y + oy*w.w;
#pragma unroll
    for (int off=32; off; off>>=1){
      p0 += __shfl_xor(p0, off, 64);
      p1 += __shfl_xor(p1, off, 64);
    }
    if (lane == 0){
      out[node*2+0] = p0 + bo[0];
      out[node*2+1] = p1 + bo[1];
    }
  }
}

// =====================================================================
extern "C" void kernel_launch(void* const* d_in, const int* in_sizes, int n_in,
                              void* d_out, int out_size, void* d_ws, size_t ws_size,
                              hipStream_t stream){
  const float* x      = (const float*)d_in[0];
  const int*   ei     = (const int*)d_in[1];
  const float* W_in   = (const float*)d_in[2];
  const float* b_in   = (const float*)d_in[3];
  const float* W_out  = (const float*)d_in[4];
  const float* b_out  = (const float*)d_in[5];
  const float* Wc[3] = {(const float*)d_in[6],  (const float*)d_in[10], (const float*)d_in[14]};
  const float* bc[3] = {(const float*)d_in[7],  (const float*)d_in[11], (const float*)d_in[15]};
  const float* g[3]  = {(const float*)d_in[8],  (const float*)d_in[12], (const float*)d_in[16]};
  const float* be[3] = {(const float*)d_in[9],  (const float*)d_in[13], (const float*)d_in[17]};
  const int n = in_sizes[0] / 64;
  const int E = in_sizes[1] / 2;
  const int NB  = (n + 511) >> BSH;
  const int NCH = (E + CHUNK - 1) / CHUNK;

  char* ws = (char*)d_ws;
  size_t off = 0;
  auto alloc = [&](size_t bytes)->char*{
    char* p = ws + off;
    off += (bytes + 511) & ~size_t(511);
    return p;
  };
  float* dinv   = (float*)alloc((size_t)n*4);
  int*   rp     = (int*)  alloc((size_t)(n+1)*4);
  int*   col    = (int*)  alloc((size_t)E*4);
  unsigned* pairs = (unsigned*)alloc((size_t)E*4);
  int*   bh     = (int*)  alloc((size_t)NB*NCH*4);
  int*   btot   = (int*)  alloc((size_t)NB*4);
  int*   bstart = (int*)  alloc((size_t)(NB+1)*4);
  unsigned short* hB  = (unsigned short*)alloc((size_t)n*128*2);
  unsigned short* rows= (unsigned short*)alloc((size_t)n*128*2);
  unsigned short* Wt[3];
  for (int l = 0; l < 3; ++l) Wt[l] = (unsigned short*)alloc(128*128*2);
  unsigned short* Wti = (unsigned short*)alloc(128*64*2);
  (void)ws_size; (void)n_in; (void)out_size;

  // CSR build
  k_bhist   <<<NCH, 256, 0, stream>>>(ei, E, n, NB, NCH, bh);
  k_scanB1  <<<NB, 256, 0, stream>>>(bh, btot, NCH);
  k_scanB2  <<<1, 512, 0, stream>>>(btot, bstart, NB, E, rp, n);
  k_bscatter<<<NCH, 256, 0, stream>>>(ei, E, n, NB, NCH, bh, bstart, pairs);
  k_bnode   <<<NB, 256, 0, stream>>>(pairs, bstart, rp, dinv, col, n);

  // weight preps
  k_prepAll<<<224, 256, 0, stream>>>(Wc[0], Wc[1], Wc[2], W_in, Wt[0], Wt[1], Wt[2], Wti);

  k_gemm_in_mfma<<<(n+63)/64, 256, 0, stream>>>(x, Wti, b_in, hB, n);
  for (int l = 0; l < 3; ++l){
    k_gemm_h_mfma<<<(n+63)/64, 256, 0, stream>>>(hB, Wt[l], dinv, rows, n);
    if (l < 2)
      k_agg_ln<0><<<(n+3)/4, 256, 0, stream>>>(rows, hB, dinv, rp, col,
                bc[l], g[l], be[l], nullptr, nullptr, nullptr, n);
    else
      k_agg_ln<1><<<(n+3)/4, 256, 0, stream>>>(rows, hB, dinv, rp, col,
                bc[l], g[l], be[l], W_out, b_out, (float*)d_out, n);
  }
}